// Round 5
// baseline (308.416 us; speedup 1.0000x reference)
//
#include <hip/hip_runtime.h>
#include <hip/hip_bf16.h>

#define NB 2
#define NL 4096
#define ND 512
#define NH 8
#define NDK 64
#define NM (NB * NL)   // 8192

typedef short bf16x8_t __attribute__((ext_vector_type(8)));
typedef float f32x4_t __attribute__((ext_vector_type(4)));

// fp32 -> bf16 bits, round-to-nearest-even
static __device__ __forceinline__ unsigned short f2bs(float f) {
  union { float f; unsigned u; } c; c.f = f;
  unsigned r = c.u + 0x7fffu + ((c.u >> 16) & 1u);
  return (unsigned short)(r >> 16);
}
static __device__ __forceinline__ float bs2f(unsigned short s) {
  union { unsigned u; float f; } c; c.u = ((unsigned)s) << 16; return c.f;
}
// pack two fp32 -> packed bf16 pair (RTNE, hardware v_cvt_pk on gfx950)
static __device__ __forceinline__ unsigned pk_bf16(float a, float b) {
  union { __hip_bfloat162 h; unsigned u; } c;
  c.h = __float22bfloat162_rn(make_float2(a, b));
  return c.u;
}

// ---------- pre-pass: round q,k,v fp32 -> bf16 planes (one launch, y=3) ----------
__global__ __launch_bounds__(256)
void round3_kernel(const float* __restrict__ s0, const float* __restrict__ s1,
                   const float* __restrict__ s2, unsigned short* __restrict__ d0,
                   unsigned short* __restrict__ d1, unsigned short* __restrict__ d2)
{
  const float* s = blockIdx.y == 0 ? s0 : (blockIdx.y == 1 ? s1 : s2);
  unsigned short* d = blockIdx.y == 0 ? d0 : (blockIdx.y == 1 ? d1 : d2);
  const size_t i = ((size_t)blockIdx.x * 256 + threadIdx.x) * 8;
  const float4 f0 = *(const float4*)(s + i);
  const float4 f1 = *(const float4*)(s + i + 4);
  uint4 o;
  o.x = (unsigned)f2bs(f0.x) | ((unsigned)f2bs(f0.y) << 16);
  o.y = (unsigned)f2bs(f0.z) | ((unsigned)f2bs(f0.w) << 16);
  o.z = (unsigned)f2bs(f1.x) | ((unsigned)f2bs(f1.y) << 16);
  o.w = (unsigned)f2bs(f1.z) | ((unsigned)f2bs(f1.w) << 16);
  *(uint4*)(d + i) = o;
}

// ---------- pre-pass: W[k][n] fp32 -> transposed hi/lo bf16 planes [n][k] ----------
struct WArgs {
  const float* W[4];
  unsigned short* Th[4];
  unsigned short* Tl[4];
};
__global__ __launch_bounds__(256)
void wsplit_kernel(WArgs a)
{
  const int z = blockIdx.z;
  const float* __restrict__ W = a.W[z];
  const int tid = threadIdx.x;
  const int n = blockIdx.x * 64 + (tid & 63);
  const int kb = blockIdx.y * 64 + (tid >> 6) * 16;
  unsigned short h[16], l[16];
#pragma unroll
  for (int u = 0; u < 16; ++u) {
    const float x = W[(size_t)(kb + u) * ND + n];
    h[u] = f2bs(x);
    l[u] = f2bs(x - bs2f(h[u]));
  }
  unsigned wh[8], wl[8];
#pragma unroll
  for (int p = 0; p < 8; ++p) {
    wh[p] = (unsigned)h[2 * p] | ((unsigned)h[2 * p + 1] << 16);
    wl[p] = (unsigned)l[2 * p] | ((unsigned)l[2 * p + 1] << 16);
  }
  unsigned short* th = a.Th[z] + (size_t)n * ND + kb;
  unsigned short* tl = a.Tl[z] + (size_t)n * ND + kb;
  *(uint4*)th = make_uint4(wh[0], wh[1], wh[2], wh[3]);
  *(uint4*)(th + 8) = make_uint4(wh[4], wh[5], wh[6], wh[7]);
  *(uint4*)tl = make_uint4(wl[0], wl[1], wl[2], wl[3]);
  *(uint4*)(tl + 8) = make_uint4(wl[4], wl[5], wl[6], wl[7]);
}

// ---------- split-bf16 MFMA GEMM core (unchanged from R4) ----------
template <bool ASPLIT, bool HEADOUT>
__device__ __forceinline__ void gemm_core(
    const unsigned short* __restrict__ Ahi, const unsigned short* __restrict__ Alo,
    const unsigned short* __restrict__ Bh, const unsigned short* __restrict__ Bl,
    const float* __restrict__ bias, unsigned short* __restrict__ outH,
    float* __restrict__ outF, int m0, int n0)
{
  __shared__ unsigned short AH[128][40];
  __shared__ unsigned short AL[128][40];
  __shared__ unsigned short BHs[64][40];
  __shared__ unsigned short BLs[64][40];

  const int tid = threadIdx.x;
  const int lane = tid & 63, w = tid >> 6;
  const int m = lane & 15, quad = lane >> 4;

  f32x4_t acc[2][4];
#pragma unroll
  for (int i = 0; i < 2; ++i)
#pragma unroll
    for (int j = 0; j < 4; ++j) acc[i][j] = (f32x4_t){0.f, 0.f, 0.f, 0.f};

  for (int k0 = 0; k0 < ND; k0 += 32) {
    __syncthreads();
    {
      const int r = tid >> 1, hf = (tid & 1) * 16;
      const unsigned short* s = Ahi + (size_t)(m0 + r) * ND + k0 + hf;
      *(uint4*)&AH[r][hf] = *(const uint4*)s;
      *(uint4*)&AH[r][hf + 8] = *(const uint4*)(s + 8);
      if constexpr (ASPLIT) {
        const unsigned short* s2 = Alo + (size_t)(m0 + r) * ND + k0 + hf;
        *(uint4*)&AL[r][hf] = *(const uint4*)s2;
        *(uint4*)&AL[r][hf + 8] = *(const uint4*)(s2 + 8);
      }
    }
    {
      const int r = tid >> 2, ch = (tid & 3) * 8;
      *(uint4*)&BHs[r][ch] = *(const uint4*)(Bh + (size_t)(n0 + r) * ND + k0 + ch);
      *(uint4*)&BLs[r][ch] = *(const uint4*)(Bl + (size_t)(n0 + r) * ND + k0 + ch);
    }
    __syncthreads();

    bf16x8_t ah[2], al[2], bh[4], bl[4];
#pragma unroll
    for (int i = 0; i < 2; ++i) {
      ah[i] = *(const bf16x8_t*)&AH[w * 32 + 16 * i + m][quad * 8];
      if constexpr (ASPLIT) al[i] = *(const bf16x8_t*)&AL[w * 32 + 16 * i + m][quad * 8];
    }
#pragma unroll
    for (int j = 0; j < 4; ++j) {
      bh[j] = *(const bf16x8_t*)&BHs[16 * j + m][quad * 8];
      bl[j] = *(const bf16x8_t*)&BLs[16 * j + m][quad * 8];
    }
#pragma unroll
    for (int i = 0; i < 2; ++i)
#pragma unroll
      for (int j = 0; j < 4; ++j) {
        acc[i][j] = __builtin_amdgcn_mfma_f32_16x16x32_bf16(ah[i], bh[j], acc[i][j], 0, 0, 0);
        acc[i][j] = __builtin_amdgcn_mfma_f32_16x16x32_bf16(ah[i], bl[j], acc[i][j], 0, 0, 0);
        if constexpr (ASPLIT)
          acc[i][j] = __builtin_amdgcn_mfma_f32_16x16x32_bf16(al[i], bh[j], acc[i][j], 0, 0, 0);
      }
  }

#pragma unroll
  for (int i = 0; i < 2; ++i)
#pragma unroll
    for (int r = 0; r < 4; ++r) {
      const int mg = m0 + w * 32 + 16 * i + quad * 4 + r;
#pragma unroll
      for (int j = 0; j < 4; ++j) {
        const int n = n0 + 16 * j + m;
        const float c = acc[i][j][r] + bias[n];
        if constexpr (HEADOUT) {
          const int b = mg >> 12, l = mg & (NL - 1);
          const int h = n >> 6, d = n & (NDK - 1);
          outH[(((size_t)(b * NH + h)) * NL + l) * NDK + d] = f2bs(c);
        } else {
          outF[(size_t)mg * ND + n] = c;
        }
      }
    }
}

struct ProjArgs {
  const unsigned short* A[3];
  const unsigned short* Bh[3];
  const unsigned short* Bl[3];
  const float* bias[3];
  unsigned short* out[3];
};
__global__ __launch_bounds__(256)
void gemm_proj_kernel(ProjArgs a)
{
  const int z = blockIdx.z;
  gemm_core<false, true>(a.A[z], nullptr, a.Bh[z], a.Bl[z], a.bias[z], a.out[z],
                         nullptr, blockIdx.x * 128, blockIdx.y * 64);
}
__global__ __launch_bounds__(256)
void gemm_out_kernel(const unsigned short* __restrict__ Ahi,
                     const unsigned short* __restrict__ Alo,
                     const unsigned short* __restrict__ Bh,
                     const unsigned short* __restrict__ Bl,
                     const float* __restrict__ bias, float* __restrict__ out)
{
  gemm_core<true, false>(Ahi, Alo, Bh, Bl, bias, nullptr, out,
                         blockIdx.x * 128, blockIdx.y * 64);
}

// ---------- MFMA bf16 flash attention, 128-q tiles, 2 m-tiles per wave ----------
// Block = (b,h, 128-query tile), 4 waves; wave w owns q rows w*32..w*32+31
// as two MFMA m-tiles (q=base+m, q=base+16+m). P bounce is pair-packed:
// one bf16 word holds both m-tiles' P for a (q,key) column pair.
__global__ __launch_bounds__(256, 4)
void attn_kernel(const unsigned short* __restrict__ qh, const unsigned short* __restrict__ kh,
                 const unsigned short* __restrict__ vh, unsigned short* __restrict__ ctxh,
                 unsigned short* __restrict__ ctxl)
{
  __shared__ unsigned short Ks[64][72];  // [key][d] (stride 36 words = 4 mod 32: free)
  __shared__ unsigned short Vt[64][72];  // [d][key]
  __shared__ unsigned Pt[64][67];        // [key][q-pair word], stride 67: <=2-way reads

  const int tid = threadIdx.x;
  const int w = tid >> 6;
  const int lane = tid & 63;
  const int m = lane & 15;
  const int quad = lane >> 4;

  const int bid = blockIdx.x;
  const int qt = bid & 31;               // 32 q-tiles of 128
  const int bh = bid >> 5;               // b*NH + h
  const unsigned short* qb = qh + (size_t)bh * NL * NDK;
  const unsigned short* kb = kh + (size_t)bh * NL * NDK;
  const unsigned short* vb = vh + (size_t)bh * NL * NDK;

  // Q A-frags for both m-tiles (loop-invariant)
  bf16x8_t aq[2][2];
#pragma unroll
  for (int mt = 0; mt < 2; ++mt) {
    const unsigned short* qsrc =
        qb + (size_t)(qt * 128 + w * 32 + mt * 16 + m) * NDK + quad * 8;
    aq[mt][0] = *(const bf16x8_t*)(qsrc);
    aq[mt][1] = *(const bf16x8_t*)(qsrc + 32);
  }

  f32x4_t o[2][4];
#pragma unroll
  for (int mt = 0; mt < 2; ++mt)
#pragma unroll
    for (int nt = 0; nt < 4; ++nt) o[mt][nt] = (f32x4_t){0.f, 0.f, 0.f, 0.f};
  float lacc[2][4] = {};

  const int kr = tid >> 2;
  const int kc = (tid & 3) * 16;
  const int vkp = lane & 31;
  const int vd0 = w * 16 + (lane >> 5) * 8;

  for (int kt = 0; kt < 64; ++kt) {
    __syncthreads();
    {  // K tile copy
      const unsigned short* src = kb + (size_t)(kt * 64 + kr) * NDK + kc;
      *(uint4*)&Ks[kr][kc] = *(const uint4*)src;
      *(uint4*)&Ks[kr][kc + 8] = *(const uint4*)(src + 8);
    }
    {  // V tile -> transposed [d][key]
      const unsigned short* s0 = vb + (size_t)(kt * 64 + 2 * vkp) * NDK + vd0;
      const uint4 a = *(const uint4*)(s0);
      const uint4 b = *(const uint4*)(s0 + NDK);
      const unsigned aw[4] = {a.x, a.y, a.z, a.w};
      const unsigned bw[4] = {b.x, b.y, b.z, b.w};
#pragma unroll
      for (int u = 0; u < 4; ++u) {
        const unsigned lo = (aw[u] & 0xffffu) | (bw[u] << 16);
        const unsigned hi = (aw[u] >> 16) | (bw[u] & 0xffff0000u);
        *(unsigned*)&Vt[vd0 + 2 * u][2 * vkp] = lo;
        *(unsigned*)&Vt[vd0 + 2 * u + 1][2 * vkp] = hi;
      }
    }
    __syncthreads();

    // S = Q K^T for both m-tiles; exp; pair-pack; one b128 Pt write per nt
#pragma unroll
    for (int nt = 0; nt < 4; ++nt) {
      const bf16x8_t b0 = *(const bf16x8_t*)&Ks[16 * nt + m][quad * 8];
      const bf16x8_t b1 = *(const bf16x8_t*)&Ks[16 * nt + m][quad * 8 + 32];
      f32x4_t s0 = (f32x4_t){0.f, 0.f, 0.f, 0.f};
      s0 = __builtin_amdgcn_mfma_f32_16x16x32_bf16(aq[0][0], b0, s0, 0, 0, 0);
      s0 = __builtin_amdgcn_mfma_f32_16x16x32_bf16(aq[0][1], b1, s0, 0, 0, 0);
      f32x4_t s1 = (f32x4_t){0.f, 0.f, 0.f, 0.f};
      s1 = __builtin_amdgcn_mfma_f32_16x16x32_bf16(aq[1][0], b0, s1, 0, 0, 0);
      s1 = __builtin_amdgcn_mfma_f32_16x16x32_bf16(aq[1][1], b1, s1, 0, 0, 0);
      unsigned pw[4];
#pragma unroll
      for (int r = 0; r < 4; ++r) {
        const float p0 = __expf(s0[r] * 0.125f);
        const float p1 = __expf(s1[r] * 0.125f);
        lacc[0][r] += p0;
        lacc[1][r] += p1;
        pw[r] = pk_bf16(p0, p1);
      }
      *(uint4*)&Pt[16 * nt + m][w * 16 + quad * 4] =
          make_uint4(pw[0], pw[1], pw[2], pw[3]);
    }
    // Pt is wave-private (each wave writes/reads only its own 16 word-columns),
    // so no barrier needed; compiler inserts lgkmcnt waits for the data dep.

    // O += P V : two 32-key chunks; each Pt word feeds BOTH m-tiles' A-frags
#pragma unroll
    for (int kb2 = 0; kb2 < 2; ++kb2) {
      unsigned pwv[8];
#pragma unroll
      for (int j = 0; j < 8; ++j)
        pwv[j] = Pt[kb2 * 32 + quad * 8 + j][w * 16 + m];
      union { bf16x8_t v; unsigned d[4]; } pa0, pa1;
#pragma unroll
      for (int t = 0; t < 4; ++t) {
        pa0.d[t] = (pwv[2 * t] & 0xffffu) | (pwv[2 * t + 1] << 16);
        pa1.d[t] = (pwv[2 * t] >> 16) | (pwv[2 * t + 1] & 0xffff0000u);
      }
#pragma unroll
      for (int nt = 0; nt < 4; ++nt) {
        const bf16x8_t vb0 = *(const bf16x8_t*)&Vt[16 * nt + m][kb2 * 32 + quad * 8];
        o[0][nt] = __builtin_amdgcn_mfma_f32_16x16x32_bf16(pa0.v, vb0, o[0][nt], 0, 0, 0);
        o[1][nt] = __builtin_amdgcn_mfma_f32_16x16x32_bf16(pa1.v, vb0, o[1][nt], 0, 0, 0);
      }
    }
  }

  // finalize
#pragma unroll
  for (int mt = 0; mt < 2; ++mt)
#pragma unroll
    for (int r = 0; r < 4; ++r) {
#pragma unroll
      for (int sh = 1; sh < 16; sh <<= 1) lacc[mt][r] += __shfl_xor(lacc[mt][r], sh);
      lacc[mt][r] = 1.0f / lacc[mt][r];
    }

  const int b = bh >> 3, h = bh & 7;
#pragma unroll
  for (int mt = 0; mt < 2; ++mt)
#pragma unroll
    for (int r = 0; r < 4; ++r) {
      const int q = qt * 128 + w * 32 + mt * 16 + quad * 4 + r;
#pragma unroll
      for (int nt = 0; nt < 4; ++nt) {
        const float x = o[mt][nt][r] * lacc[mt][r];
        const unsigned short hx = f2bs(x);
        const unsigned short lx = f2bs(x - bs2f(hx));
        const size_t idx = ((size_t)(b * NL + q)) * ND + h * 64 + 16 * nt + m;
        ctxh[idx] = hx;
        ctxl[idx] = lx;
      }
    }
}

extern "C" void kernel_launch(void* const* d_in, const int* in_sizes, int n_in,
                              void* d_out, int out_size, void* d_ws, size_t ws_size,
                              hipStream_t stream)
{
  const float* q  = (const float*)d_in[0];
  const float* k  = (const float*)d_in[1];
  const float* v  = (const float*)d_in[2];
  const float* Wq = (const float*)d_in[3];
  const float* bq = (const float*)d_in[4];
  const float* Wk = (const float*)d_in[5];
  const float* bk = (const float*)d_in[6];
  const float* Wv = (const float*)d_in[7];
  const float* bv = (const float*)d_in[8];
  const float* Wo = (const float*)d_in[9];
  const float* bo = (const float*)d_in[10];

  const size_t PLANE = (size_t)NM * ND;
  unsigned short* qb = (unsigned short*)d_ws;
  unsigned short* kb = qb + PLANE;
  unsigned short* vb = kb + PLANE;
  unsigned short* wt = vb + PLANE;
  unsigned short* qhp = wt + 8 * (size_t)ND * ND;
  unsigned short* khp = qhp + PLANE;
  unsigned short* vhp = khp + PLANE;
  unsigned short* ctxh = qb;   // alias (qb/kb dead after proj)
  unsigned short* ctxl = kb;

  unsigned short* wth[4], *wtl[4];
  for (int i = 0; i < 4; ++i) {
    wth[i] = wt + (size_t)(2 * i) * ND * ND;
    wtl[i] = wt + (size_t)(2 * i + 1) * ND * ND;
  }

  // 1) round q,k,v to bf16 planes
  round3_kernel<<<dim3(PLANE / (256 * 8), 3), 256, 0, stream>>>(q, k, v, qb, kb, vb);

  // 2) transpose+split all four weight matrices
  WArgs wa;
  wa.W[0] = Wq; wa.W[1] = Wk; wa.W[2] = Wv; wa.W[3] = Wo;
  for (int i = 0; i < 4; ++i) { wa.Th[i] = wth[i]; wa.Tl[i] = wtl[i]; }
  wsplit_kernel<<<dim3(8, 8, 4), 256, 0, stream>>>(wa);

  // 3) three projection GEMMs (2-term split)
  ProjArgs pa;
  pa.A[0] = qb; pa.A[1] = kb; pa.A[2] = vb;
  pa.Bh[0] = wth[0]; pa.Bl[0] = wtl[0];
  pa.Bh[1] = wth[1]; pa.Bl[1] = wtl[1];
  pa.Bh[2] = wth[2]; pa.Bl[2] = wtl[2];
  pa.bias[0] = bq; pa.bias[1] = bk; pa.bias[2] = bv;
  pa.out[0] = qhp; pa.out[1] = khp; pa.out[2] = vhp;
  gemm_proj_kernel<<<dim3(NM / 128, ND / 64, 3), 256, 0, stream>>>(pa);

  // 4) attention (128-q tiles)
  attn_kernel<<<dim3(NB * NH * (NL / 128)), 256, 0, stream>>>(qhp, khp, vhp, ctxh, ctxl);

  // 5) output GEMM (3-term split, fp32 out)
  gemm_out_kernel<<<dim3(NM / 128, ND / 64), 256, 0, stream>>>(
      ctxh, ctxl, wth[3], wtl[3], bo, (float*)d_out);
}

// Round 6
// 303.421 us; speedup vs baseline: 1.0165x; 1.0165x over previous
//
#include <hip/hip_runtime.h>
#include <hip/hip_bf16.h>

#define NB 2
#define NL 4096
#define ND 512
#define NH 8
#define NDK 64
#define NM (NB * NL)   // 8192

typedef short bf16x8_t __attribute__((ext_vector_type(8)));
typedef float f32x4_t __attribute__((ext_vector_type(4)));

// fp32 -> bf16 bits, round-to-nearest-even
static __device__ __forceinline__ unsigned short f2bs(float f) {
  union { float f; unsigned u; } c; c.f = f;
  unsigned r = c.u + 0x7fffu + ((c.u >> 16) & 1u);
  return (unsigned short)(r >> 16);
}
static __device__ __forceinline__ float bs2f(unsigned short s) {
  union { unsigned u; float f; } c; c.u = ((unsigned)s) << 16; return c.f;
}
// pack two fp32 -> packed bf16 pair (RTNE)
static __device__ __forceinline__ unsigned pk_bf16(float a, float b) {
  union { __hip_bfloat162 h; unsigned u; } c;
  c.h = __float22bfloat162_rn(make_float2(a, b));
  return c.u;
}

// ---------- pre-pass: W[k][n] fp32 -> transposed hi/lo bf16 planes [n][k] ----------
struct WArgs {
  const float* W[4];
  unsigned short* Th[4];
  unsigned short* Tl[4];
};
__global__ __launch_bounds__(256)
void wsplit_kernel(WArgs a)
{
  const int z = blockIdx.z;
  const float* __restrict__ W = a.W[z];
  const int tid = threadIdx.x;
  const int n = blockIdx.x * 64 + (tid & 63);
  const int kb = blockIdx.y * 64 + (tid >> 6) * 16;
  unsigned short h[16], l[16];
#pragma unroll
  for (int u = 0; u < 16; ++u) {
    const float x = W[(size_t)(kb + u) * ND + n];
    h[u] = f2bs(x);
    l[u] = f2bs(x - bs2f(h[u]));
  }
  unsigned wh[8], wl[8];
#pragma unroll
  for (int p = 0; p < 8; ++p) {
    wh[p] = (unsigned)h[2 * p] | ((unsigned)h[2 * p + 1] << 16);
    wl[p] = (unsigned)l[2 * p] | ((unsigned)l[2 * p + 1] << 16);
  }
  unsigned short* th = a.Th[z] + (size_t)n * ND + kb;
  unsigned short* tl = a.Tl[z] + (size_t)n * ND + kb;
  *(uint4*)th = make_uint4(wh[0], wh[1], wh[2], wh[3]);
  *(uint4*)(th + 8) = make_uint4(wh[4], wh[5], wh[6], wh[7]);
  *(uint4*)tl = make_uint4(wl[0], wl[1], wl[2], wl[3]);
  *(uint4*)(tl + 8) = make_uint4(wl[4], wl[5], wl[6], wl[7]);
}

// ---------- split-bf16 MFMA GEMM core ----------
// AFP32: A is fp32, converted to bf16 (RTNE) during LDS staging.
// ASPLIT: A has hi+lo bf16 planes -> 3-term product. HEADOUT: bf16 [B][H][L][64].
template <bool AFP32, bool ASPLIT, bool HEADOUT>
__device__ __forceinline__ void gemm_core(
    const void* __restrict__ Aptr, const unsigned short* __restrict__ Alo,
    const unsigned short* __restrict__ Bh, const unsigned short* __restrict__ Bl,
    const float* __restrict__ bias, unsigned short* __restrict__ outH,
    float* __restrict__ outF, int m0, int n0)
{
  __shared__ unsigned short AH[128][40];
  __shared__ unsigned short AL[128][40];
  __shared__ unsigned short BHs[64][40];
  __shared__ unsigned short BLs[64][40];

  const int tid = threadIdx.x;
  const int lane = tid & 63, w = tid >> 6;
  const int m = lane & 15, quad = lane >> 4;

  f32x4_t acc[2][4];
#pragma unroll
  for (int i = 0; i < 2; ++i)
#pragma unroll
    for (int j = 0; j < 4; ++j) acc[i][j] = (f32x4_t){0.f, 0.f, 0.f, 0.f};

  for (int k0 = 0; k0 < ND; k0 += 32) {
    __syncthreads();
    {  // A tile: 128 rows x 32 elems
      const int r = tid >> 1, hf = (tid & 1) * 16;
      if constexpr (AFP32) {
        const float* s = (const float*)Aptr + (size_t)(m0 + r) * ND + k0 + hf;
        const float4 f0 = *(const float4*)s;
        const float4 f1 = *(const float4*)(s + 4);
        const float4 f2 = *(const float4*)(s + 8);
        const float4 f3 = *(const float4*)(s + 12);
        uint4 u0, u1;
        u0.x = pk_bf16(f0.x, f0.y); u0.y = pk_bf16(f0.z, f0.w);
        u0.z = pk_bf16(f1.x, f1.y); u0.w = pk_bf16(f1.z, f1.w);
        u1.x = pk_bf16(f2.x, f2.y); u1.y = pk_bf16(f2.z, f2.w);
        u1.z = pk_bf16(f3.x, f3.y); u1.w = pk_bf16(f3.z, f3.w);
        *(uint4*)&AH[r][hf] = u0;
        *(uint4*)&AH[r][hf + 8] = u1;
      } else {
        const unsigned short* s = (const unsigned short*)Aptr + (size_t)(m0 + r) * ND + k0 + hf;
        *(uint4*)&AH[r][hf] = *(const uint4*)s;
        *(uint4*)&AH[r][hf + 8] = *(const uint4*)(s + 8);
        if constexpr (ASPLIT) {
          const unsigned short* s2 = Alo + (size_t)(m0 + r) * ND + k0 + hf;
          *(uint4*)&AL[r][hf] = *(const uint4*)s2;
          *(uint4*)&AL[r][hf + 8] = *(const uint4*)(s2 + 8);
        }
      }
    }
    {  // B tiles hi+lo
      const int r = tid >> 2, ch = (tid & 3) * 8;
      *(uint4*)&BHs[r][ch] = *(const uint4*)(Bh + (size_t)(n0 + r) * ND + k0 + ch);
      *(uint4*)&BLs[r][ch] = *(const uint4*)(Bl + (size_t)(n0 + r) * ND + k0 + ch);
    }
    __syncthreads();

    bf16x8_t ah[2], al[2], bh[4], bl[4];
#pragma unroll
    for (int i = 0; i < 2; ++i) {
      ah[i] = *(const bf16x8_t*)&AH[w * 32 + 16 * i + m][quad * 8];
      if constexpr (ASPLIT) al[i] = *(const bf16x8_t*)&AL[w * 32 + 16 * i + m][quad * 8];
    }
#pragma unroll
    for (int j = 0; j < 4; ++j) {
      bh[j] = *(const bf16x8_t*)&BHs[16 * j + m][quad * 8];
      bl[j] = *(const bf16x8_t*)&BLs[16 * j + m][quad * 8];
    }
#pragma unroll
    for (int i = 0; i < 2; ++i)
#pragma unroll
      for (int j = 0; j < 4; ++j) {
        acc[i][j] = __builtin_amdgcn_mfma_f32_16x16x32_bf16(ah[i], bh[j], acc[i][j], 0, 0, 0);
        acc[i][j] = __builtin_amdgcn_mfma_f32_16x16x32_bf16(ah[i], bl[j], acc[i][j], 0, 0, 0);
        if constexpr (ASPLIT)
          acc[i][j] = __builtin_amdgcn_mfma_f32_16x16x32_bf16(al[i], bh[j], acc[i][j], 0, 0, 0);
      }
  }

#pragma unroll
  for (int i = 0; i < 2; ++i)
#pragma unroll
    for (int r = 0; r < 4; ++r) {
      const int mg = m0 + w * 32 + 16 * i + quad * 4 + r;
#pragma unroll
      for (int j = 0; j < 4; ++j) {
        const int n = n0 + 16 * j + m;
        const float c = acc[i][j][r] + bias[n];
        if constexpr (HEADOUT) {
          const int b = mg >> 12, l = mg & (NL - 1);
          const int h = n >> 6, d = n & (NDK - 1);
          outH[(((size_t)(b * NH + h)) * NL + l) * NDK + d] = f2bs(c);
        } else {
          outF[(size_t)mg * ND + n] = c;
        }
      }
    }
}

struct ProjArgs {
  const float* A[3];
  const unsigned short* Bh[3];
  const unsigned short* Bl[3];
  const float* bias[3];
  unsigned short* out[3];
};
__global__ __launch_bounds__(256)
void gemm_proj_kernel(ProjArgs a)
{
  const int z = blockIdx.z;
  gemm_core<true, false, true>(a.A[z], nullptr, a.Bh[z], a.Bl[z], a.bias[z], a.out[z],
                               nullptr, blockIdx.x * 128, blockIdx.y * 64);
}
__global__ __launch_bounds__(256)
void gemm_out_kernel(const unsigned short* __restrict__ Ahi,
                     const unsigned short* __restrict__ Alo,
                     const unsigned short* __restrict__ Bh,
                     const unsigned short* __restrict__ Bl,
                     const float* __restrict__ bias, float* __restrict__ out)
{
  gemm_core<false, true, false>(Ahi, Alo, Bh, Bl, bias, nullptr, out,
                                blockIdx.x * 128, blockIdx.y * 64);
}

// ---------- MFMA bf16 flash attention, 128-q tiles, 2-way KEY-SPLIT ----------
// Grid 1024: block = (bh, qt, half). No max-subtraction -> (o_unnorm, l) are
// additive across key halves; merge kernel combines. K/V register prefetch.
#define EXP2C 0.18033688011112042f  // 0.125 * log2(e)
__global__ __launch_bounds__(256, 4)
void attn_kernel(const unsigned short* __restrict__ qh, const unsigned short* __restrict__ kh,
                 const unsigned short* __restrict__ vh, float* __restrict__ op,
                 float* __restrict__ lp)
{
  __shared__ unsigned short Ks[64][72];  // [key][d]
  __shared__ unsigned short Vt[64][72];  // [d][key]
  __shared__ unsigned Pt[64][67];        // [key][q-pair word]

  const int tid = threadIdx.x;
  const int w = tid >> 6;
  const int lane = tid & 63;
  const int m = lane & 15;
  const int quad = lane >> 4;

  const int bid = blockIdx.x;
  const int half = bid & 1;
  const int qt = (bid >> 1) & 31;
  const int bh = bid >> 6;               // b*NH + h
  const int kt0 = half * 32, kt1 = kt0 + 32;
  const unsigned short* qb = qh + (size_t)bh * NL * NDK;
  const unsigned short* kb = kh + (size_t)bh * NL * NDK;
  const unsigned short* vb = vh + (size_t)bh * NL * NDK;

  // Q A-frags for both m-tiles (loop-invariant)
  bf16x8_t aq[2][2];
#pragma unroll
  for (int mt = 0; mt < 2; ++mt) {
    const unsigned short* qsrc =
        qb + (size_t)(qt * 128 + w * 32 + mt * 16 + m) * NDK + quad * 8;
    aq[mt][0] = *(const bf16x8_t*)(qsrc);
    aq[mt][1] = *(const bf16x8_t*)(qsrc + 32);
  }

  f32x4_t o[2][4];
#pragma unroll
  for (int mt = 0; mt < 2; ++mt)
#pragma unroll
    for (int nt = 0; nt < 4; ++nt) o[mt][nt] = (f32x4_t){0.f, 0.f, 0.f, 0.f};
  float lacc[2][4] = {};

  const int kr = tid >> 2;
  const int kc = (tid & 3) * 16;
  const int vkp = lane & 31;
  const int vd0 = w * 16 + (lane >> 5) * 8;

  // prefetch first K/V tile into registers
  uint4 pk0, pk1, pva, pvb;
  {
    const unsigned short* src = kb + (size_t)(kt0 * 64 + kr) * NDK + kc;
    pk0 = *(const uint4*)src;
    pk1 = *(const uint4*)(src + 8);
    const unsigned short* s0 = vb + (size_t)(kt0 * 64 + 2 * vkp) * NDK + vd0;
    pva = *(const uint4*)s0;
    pvb = *(const uint4*)(s0 + NDK);
  }

  for (int kt = kt0; kt < kt1; ++kt) {
    __syncthreads();
    {  // stage K from regs
      *(uint4*)&Ks[kr][kc] = pk0;
      *(uint4*)&Ks[kr][kc + 8] = pk1;
    }
    {  // stage V transposed from regs
      const unsigned aw[4] = {pva.x, pva.y, pva.z, pva.w};
      const unsigned bw[4] = {pvb.x, pvb.y, pvb.z, pvb.w};
#pragma unroll
      for (int u = 0; u < 4; ++u) {
        const unsigned lo = (aw[u] & 0xffffu) | (bw[u] << 16);
        const unsigned hi = (aw[u] >> 16) | (bw[u] & 0xffff0000u);
        *(unsigned*)&Vt[vd0 + 2 * u][2 * vkp] = lo;
        *(unsigned*)&Vt[vd0 + 2 * u + 1][2 * vkp] = hi;
      }
    }
    if (kt + 1 < kt1) {  // prefetch next tile (overlaps compute below)
      const unsigned short* src = kb + (size_t)((kt + 1) * 64 + kr) * NDK + kc;
      pk0 = *(const uint4*)src;
      pk1 = *(const uint4*)(src + 8);
      const unsigned short* s0 = vb + (size_t)((kt + 1) * 64 + 2 * vkp) * NDK + vd0;
      pva = *(const uint4*)s0;
      pvb = *(const uint4*)(s0 + NDK);
    }
    __syncthreads();

    // S = Q K^T for both m-tiles; exp; pair-pack; one b128 Pt write per nt
#pragma unroll
    for (int nt = 0; nt < 4; ++nt) {
      const bf16x8_t b0 = *(const bf16x8_t*)&Ks[16 * nt + m][quad * 8];
      const bf16x8_t b1 = *(const bf16x8_t*)&Ks[16 * nt + m][quad * 8 + 32];
      f32x4_t s0 = (f32x4_t){0.f, 0.f, 0.f, 0.f};
      s0 = __builtin_amdgcn_mfma_f32_16x16x32_bf16(aq[0][0], b0, s0, 0, 0, 0);
      s0 = __builtin_amdgcn_mfma_f32_16x16x32_bf16(aq[0][1], b1, s0, 0, 0, 0);
      f32x4_t s1 = (f32x4_t){0.f, 0.f, 0.f, 0.f};
      s1 = __builtin_amdgcn_mfma_f32_16x16x32_bf16(aq[1][0], b0, s1, 0, 0, 0);
      s1 = __builtin_amdgcn_mfma_f32_16x16x32_bf16(aq[1][1], b1, s1, 0, 0, 0);
      unsigned pw[4];
#pragma unroll
      for (int r = 0; r < 4; ++r) {
        const float p0 = exp2f(s0[r] * EXP2C);
        const float p1 = exp2f(s1[r] * EXP2C);
        lacc[0][r] += p0;
        lacc[1][r] += p1;
        pw[r] = pk_bf16(p0, p1);
      }
      *(uint4*)&Pt[16 * nt + m][w * 16 + quad * 4] =
          make_uint4(pw[0], pw[1], pw[2], pw[3]);
    }
    // Pt is wave-private; no barrier needed (lgkmcnt dep handles ordering)

    // O += P V
#pragma unroll
    for (int kb2 = 0; kb2 < 2; ++kb2) {
      unsigned pwv[8];
#pragma unroll
      for (int j = 0; j < 8; ++j)
        pwv[j] = Pt[kb2 * 32 + quad * 8 + j][w * 16 + m];
      union { bf16x8_t v; unsigned d[4]; } pa0, pa1;
#pragma unroll
      for (int t = 0; t < 4; ++t) {
        pa0.d[t] = (pwv[2 * t] & 0xffffu) | (pwv[2 * t + 1] << 16);
        pa1.d[t] = (pwv[2 * t] >> 16) | (pwv[2 * t + 1] & 0xffff0000u);
      }
#pragma unroll
      for (int nt = 0; nt < 4; ++nt) {
        const bf16x8_t vb0 = *(const bf16x8_t*)&Vt[16 * nt + m][kb2 * 32 + quad * 8];
        o[0][nt] = __builtin_amdgcn_mfma_f32_16x16x32_bf16(pa0.v, vb0, o[0][nt], 0, 0, 0);
        o[1][nt] = __builtin_amdgcn_mfma_f32_16x16x32_bf16(pa1.v, vb0, o[1][nt], 0, 0, 0);
      }
    }
  }

  // epilogue: unnormalized o (fp32) + partial row sums
#pragma unroll
  for (int mt = 0; mt < 2; ++mt)
#pragma unroll
    for (int r = 0; r < 4; ++r)
#pragma unroll
      for (int sh = 1; sh < 16; sh <<= 1) lacc[mt][r] += __shfl_xor(lacc[mt][r], sh);

  const size_t pbase = (size_t)(half * 16 + bh) * NL;
#pragma unroll
  for (int mt = 0; mt < 2; ++mt) {
    const int q0 = qt * 128 + w * 32 + mt * 16 + quad * 4;
    if (m == 0)
      *(float4*)&lp[pbase + q0] =
          make_float4(lacc[mt][0], lacc[mt][1], lacc[mt][2], lacc[mt][3]);
#pragma unroll
    for (int r = 0; r < 4; ++r) {
      float* dst = op + (pbase + q0 + r) * NDK;
#pragma unroll
      for (int nt = 0; nt < 4; ++nt) dst[16 * nt + m] = o[mt][nt][r];
    }
  }
}

// ---------- merge: ctx = (o0+o1)/(l0+l1), emit split-bf16 planes ----------
__global__ __launch_bounds__(256)
void merge_kernel(const float* __restrict__ op, const float* __restrict__ lp,
                  unsigned short* __restrict__ ctxh, unsigned short* __restrict__ ctxl)
{
  const size_t t = (size_t)blockIdx.x * 256 + threadIdx.x;
  const int d0 = (int)(t & 7) * 8;
  const size_t row = t >> 3;               // bh*NL + l
  const float l0 = lp[row];
  const float l1 = lp[row + (size_t)16 * NL];
  const float inv = 1.0f / (l0 + l1);
  const float* a = op + row * NDK + d0;
  const float* c = a + (size_t)16 * NL * NDK;
  const float4 a0 = *(const float4*)a, a1 = *(const float4*)(a + 4);
  const float4 c0 = *(const float4*)c, c1 = *(const float4*)(c + 4);
  const float x[8] = {(a0.x + c0.x) * inv, (a0.y + c0.y) * inv,
                      (a0.z + c0.z) * inv, (a0.w + c0.w) * inv,
                      (a1.x + c1.x) * inv, (a1.y + c1.y) * inv,
                      (a1.z + c1.z) * inv, (a1.w + c1.w) * inv};
  unsigned short hs[8], ls[8];
#pragma unroll
  for (int u = 0; u < 8; ++u) {
    hs[u] = f2bs(x[u]);
    ls[u] = f2bs(x[u] - bs2f(hs[u]));
  }
  const int bh = (int)(row >> 12), l = (int)(row & (NL - 1));
  const int b = bh >> 3, h = bh & 7;
  const size_t dst = ((size_t)(b * NL + l)) * ND + h * 64 + d0;
  uint4 uh, ul;
  uh.x = (unsigned)hs[0] | ((unsigned)hs[1] << 16);
  uh.y = (unsigned)hs[2] | ((unsigned)hs[3] << 16);
  uh.z = (unsigned)hs[4] | ((unsigned)hs[5] << 16);
  uh.w = (unsigned)hs[6] | ((unsigned)hs[7] << 16);
  ul.x = (unsigned)ls[0] | ((unsigned)ls[1] << 16);
  ul.y = (unsigned)ls[2] | ((unsigned)ls[3] << 16);
  ul.z = (unsigned)ls[4] | ((unsigned)ls[5] << 16);
  ul.w = (unsigned)ls[6] | ((unsigned)ls[7] << 16);
  *(uint4*)(ctxh + dst) = uh;
  *(uint4*)(ctxl + dst) = ul;
}

extern "C" void kernel_launch(void* const* d_in, const int* in_sizes, int n_in,
                              void* d_out, int out_size, void* d_ws, size_t ws_size,
                              hipStream_t stream)
{
  const float* q  = (const float*)d_in[0];
  const float* k  = (const float*)d_in[1];
  const float* v  = (const float*)d_in[2];
  const float* Wq = (const float*)d_in[3];
  const float* bq = (const float*)d_in[4];
  const float* Wk = (const float*)d_in[5];
  const float* bk = (const float*)d_in[6];
  const float* Wv = (const float*)d_in[7];
  const float* bv = (const float*)d_in[8];
  const float* Wo = (const float*)d_in[9];
  const float* bo = (const float*)d_in[10];

  const size_t PLANE = (size_t)NM * ND;               // 4.19M elems
  unsigned short* wt = (unsigned short*)d_ws;         // 8 x 512KB weight planes
  unsigned short* qhp = wt + 8 * (size_t)ND * ND;
  unsigned short* khp = qhp + PLANE;
  unsigned short* vhp = khp + PLANE;
  float* op = (float*)(vhp + PLANE);                  // 2 x 16.8 MB fp32 partials
  float* lp = op + 2 * (size_t)16 * NL * NDK;         // 2 x 256 KB
  unsigned short* ctxh = qhp;                         // alias (dead after attn)
  unsigned short* ctxl = khp;

  unsigned short* wth[4], *wtl[4];
  for (int i = 0; i < 4; ++i) {
    wth[i] = wt + (size_t)(2 * i) * ND * ND;
    wtl[i] = wt + (size_t)(2 * i + 1) * ND * ND;
  }

  // 1) transpose+split weight matrices
  WArgs wa;
  wa.W[0] = Wq; wa.W[1] = Wk; wa.W[2] = Wv; wa.W[3] = Wo;
  for (int i = 0; i < 4; ++i) { wa.Th[i] = wth[i]; wa.Tl[i] = wtl[i]; }
  wsplit_kernel<<<dim3(8, 8, 4), 256, 0, stream>>>(wa);

  // 2) three projection GEMMs (fp32 A converted in-staging)
  ProjArgs pa;
  pa.A[0] = q; pa.A[1] = k; pa.A[2] = v;
  pa.Bh[0] = wth[0]; pa.Bl[0] = wtl[0];
  pa.Bh[1] = wth[1]; pa.Bl[1] = wtl[1];
  pa.Bh[2] = wth[2]; pa.Bl[2] = wtl[2];
  pa.bias[0] = bq; pa.bias[1] = bk; pa.bias[2] = bv;
  pa.out[0] = qhp; pa.out[1] = khp; pa.out[2] = vhp;
  gemm_proj_kernel<<<dim3(NM / 128, ND / 64, 3), 256, 0, stream>>>(pa);

  // 3) attention, 2-way key split (1024 blocks)
  attn_kernel<<<dim3(NB * NH * (NL / 128) * 2), 256, 0, stream>>>(qhp, khp, vhp, op, lp);

  // 4) merge partials -> split-bf16 ctx planes
  merge_kernel<<<dim3((16 * NL * NDK) / (256 * 8)), 256, 0, stream>>>(op, lp, ctxh, ctxl);

  // 5) output GEMM (3-term split, fp32 out)
  gemm_out_kernel<<<dim3(NM / 128, ND / 64), 256, 0, stream>>>(
      ctxh, ctxl, wth[3], wtl[3], bo, (float*)d_out);
}